// Round 15
// baseline (3887.842 us; speedup 1.0000x reference)
//
#include <hip/hip_runtime.h>
#include <math.h>

#define HILB  4096
#define FEAT  256
#define OUTW  4098          // 4096 probs + entropy + entangle
#define GSTR  65            // planar G row stride (fallback kernel)

typedef float v2f __attribute__((ext_vector_type(2)));

__device__ __forceinline__ float sanout(float v) {
    return (v == v && fabsf(v) < 1e30f) ? v : 1e6f;  // readable failure signature
}

// ===================== kernel 1: front (round-13 body; residency 4 -> 6 blocks/CU) =======
// Front uses 64 VGPRs; cap at (256,6) is ~85 so no allocator squeeze. More resident waves
// hide the W2 L2-hit latency in the k-loop (same lever that won for eig in round 13).
__launch_bounds__(256, 6)
__global__ void qsp_front(const float* __restrict__ X,  const float* __restrict__ W1,
                          const float* __restrict__ B1, const float* __restrict__ W2,
                          const float* __restrict__ B2, const float* __restrict__ EP,
                          float* __restrict__ out, float2* __restrict__ G)
{
    __shared__ float2 vc2[8][64];          // 8 rows of M staging
    __shared__ float  sx[FEAT];
    __shared__ float  sh[48];
    __shared__ float  T8[8];
    __shared__ float  red[4];
    __shared__ float  s_inv2;

    const int tid  = threadIdx.x;
    const int b    = blockIdx.x;
    const int lane = tid & 63;
    const int wv   = tid >> 6;

    sx[tid] = X[b * FEAT + tid];
    __syncthreads();
    if (tid < 48) {
        float acc = B1[tid];
        for (int t = 0; t < FEAT; ++t) acc += sx[t] * W1[t * 48 + tid];
        sh[tid] = tanhf(acc);
    }
    if (tid == 64) {   // gate product on one thread of wave 1 (overlaps with h)
        float t00r=1.f,t00i=0.f,t01r=0.f,t01i=0.f,t10r=0.f,t10i=0.f,t11r=1.f,t11i=0.f;
        for (int g = 0; g < 33; ++g) {
            int d = g / 11, q = g % 11;
            const float* p = EP + (d * 12 + q) * 4;
            float th = p[0], ph = p[1], la = p[2], ga = p[3];
            float c  = cosf(0.5f * th), sn = sinf(0.5f * th);
            float ephr = cosf(ph), ephi = sinf(ph);
            float elar = cosf(la), elai = sinf(la);
            float egar = cosf(ga), egai = sinf(ga);
            float r00r =  c,          r00i = 0.f;
            float r01r = -elar * sn,  r01i = -elai * sn;
            float r10r =  ephr * sn,  r10i =  ephi * sn;
            float r11r =  egar * c,   r11i =  egai * c;
            float n00r = t00r*r00r - t00i*r00i + t01r*r10r - t01i*r10i;
            float n00i = t00r*r00i + t00i*r00r + t01r*r10i + t01i*r10r;
            float n01r = t00r*r01r - t00i*r01i + t01r*r11r - t01i*r11i;
            float n01i = t00r*r01i + t00i*r01r + t01r*r11i + t01i*r11r;
            float n10r = t10r*r00r - t10i*r00i + t11r*r10r - t11i*r10i;
            float n10i = t10r*r00i + t10i*r00r + t11r*r10i + t11i*r10r;
            float n11r = t10r*r01r - t10i*r01i + t11r*r11r - t11i*r11i;
            float n11i = t10r*r01i + t10i*r01r + t11r*r11i + t11i*r11r;
            t00r=n00r; t00i=n00i; t01r=n01r; t01i=n01i;
            t10r=n10r; t10i=n10i; t11r=n11r; t11i=n11i;
        }
        T8[0]=t00r; T8[1]=t00i; T8[2]=t01r; T8[3]=t01i;
        T8[4]=t10r; T8[5]=t10i; T8[6]=t11r; T8[7]=t11i;
    }
    __syncthreads();

    float accRe[16], accIm[16];
    #pragma unroll
    for (int jj = 0; jj < 16; ++jj) { accRe[jj] = 0.f; accIm[jj] = 0.f; }
    float ssq = 0.f;

    const int part = (tid >> 4) & 1;
    const int lr   = tid >> 5;
    const int c0   = (tid & 15) * 4;

    for (int it = 0; it < 8; ++it) {
        int row = it * 8 + lr;
        int j0  = part * HILB + row * 64 + c0;
        float a0 = B2[j0], a1 = B2[j0+1], a2 = B2[j0+2], a3 = B2[j0+3];
        #pragma unroll 8
        for (int k = 0; k < 48; ++k) {     // unroll-8: 8 W2 loads in flight
            float4 w4 = *(const float4*)(W2 + k * 8192 + j0);
            float hk = sh[k];
            a0 += hk * w4.x; a1 += hk * w4.y;
            a2 += hk * w4.z; a3 += hk * w4.w;
        }
        float* vf = (float*)&vc2[lr][0];
        vf[(c0+0)*2 + part] = a0;
        vf[(c0+1)*2 + part] = a1;
        vf[(c0+2)*2 + part] = a2;
        vf[(c0+3)*2 + part] = a3;
        __syncthreads();

        if (it == 0) {                     // apply gate product T to raw psi0, psi1
            if (tid == 0) {
                float2 s0 = vc2[0][0], s1 = vc2[0][1];
                float n0r = s0.x*T8[0] - s0.y*T8[1] + s1.x*T8[4] - s1.y*T8[5];
                float n0i = s0.x*T8[1] + s0.y*T8[0] + s1.x*T8[5] + s1.y*T8[4];
                float n1r = s0.x*T8[2] - s0.y*T8[3] + s1.x*T8[6] - s1.y*T8[7];
                float n1i = s0.x*T8[3] + s0.y*T8[2] + s1.x*T8[7] + s1.y*T8[6];
                vc2[0][0] = make_float2(n0r, n0i);
                vc2[0][1] = make_float2(n1r, n1i);
            }
            __syncthreads();
        }

        #pragma unroll
        for (int s = 0; s < 2; ++s) {      // raw probs out; rescaled after norm
            int jo  = tid + s * 256;
            int lr2 = jo >> 6, cc = jo & 63;
            float2 v = vc2[lr2][cc];
            float praw = v.x * v.x + v.y * v.y;
            out[(size_t)b * OUTW + it * 512 + jo] = praw;
            ssq += praw;
        }

        for (int rr = 0; rr < 8; ++rr) {   // raw Gram accumulation
            float2 vq = vc2[rr][lane];
            #pragma unroll
            for (int jj = 0; jj < 16; ++jj) {
                float2 vp = vc2[rr][wv * 16 + jj];
                accRe[jj] += vp.x * vq.x + vp.y * vq.y;
                accIm[jj] += vp.x * vq.y - vp.y * vq.x;
            }
        }
        __syncthreads();
    }

    // norm -> inv2, entropy
    {
        float v = ssq;
        #pragma unroll
        for (int off = 32; off; off >>= 1) v += __shfl_down(v, off, 64);
        if (lane == 0) red[wv] = v;
        __syncthreads();
        if (tid == 0) {
            float tot = red[0] + red[1] + red[2] + red[3];
            float nrm = sqrtf(tot);
            float inv = 1.f / fmaxf(nrm, 1e-12f);
            float i2  = inv * inv;
            s_inv2 = i2;
            float n2  = tot * i2;
            float lam = fmaxf(n2, 1e-12f);
            out[(size_t)b * OUTW + HILB] = sanout(-lam * logf(lam) + 1.1314877e-7f);
        }
        __syncthreads();
    }
    const float inv2 = s_inv2;

    // scaled G straight from registers to workspace (coalesced float2)
    float2* gb = G + (size_t)b * 4096;
    #pragma unroll
    for (int jj = 0; jj < 16; ++jj) {
        int p = wv * 16 + jj;
        gb[p * 64 + lane] = make_float2(inv2 * accRe[jj], inv2 * accIm[jj]);
    }

    // rescale own prob slots (same-thread RAW)
    #pragma unroll
    for (int i = 0; i < 16; ++i) {
        size_t idx = (size_t)b * OUTW + (i >> 1) * 512 + (i & 1) * 256 + tid;
        out[idx] = sanout(inv2 * out[idx]);
    }
}

// ========== kernel 2: eigensolve — 2 waves/matrix, packed FP32 + b128 uniform reads =======
// (round-13 proven version: 757 us, VGPR 84, (128,3)) lane r of wave w owns row r, cols
// {4s+w, 4s+2+w} packed as v2f grp/gip[s]; v/w SoA in LDS; paired s-loop -> b128 reads.
#define EIG_STEP_P(S0)                                                              \
{                                                                                   \
    const int a   = k + 1;                                                          \
    const int buf = k & 1;                                                          \
    if ((k & 1) == w) {  /* phase A: owner wave of column k */                      \
        float cr = (lane >= a) ? ncr : 0.f;                                         \
        float ci = (lane >= a) ? nci : 0.f;                                         \
        float sig = cr*cr + ci*ci;                                                  \
        _Pragma("unroll")                                                           \
        for (int off = 1; off < 64; off <<= 1) sig += __shfl_xor(sig, off, 64);     \
        float x1r = __shfl(cr, a, 64);                                              \
        float x1i = __shfl(ci, a, 64);                                              \
        float ax1 = sqrtf(x1r*x1r + x1i*x1i);                                       \
        float nrmv = sqrtf(sig);                                                    \
        float tauo = 0.f, prr = 1.f, pii = 0.f;                                     \
        if (sig > 1e-30f) {                                                         \
            tauo = 1.f / (sig + nrmv * ax1);                                        \
            if (ax1 > 1e-30f) { prr = x1r / ax1; pii = x1i / ax1; }                 \
        }                                                                           \
        float vro = cr, vio = ci;                                                   \
        if (lane == a) { vro += prr * nrmv; vio += pii * nrmv; }                    \
        vxA[buf][lp][lt] = vro;                                                     \
        vyA[buf][lp][lt] = vio;                                                     \
        if (lane == 0) { taulds[buf] = tauo; eslds[a] = sig; }                      \
    }                                                                               \
    __syncthreads();                        /* barrier 1: v, tau visible */         \
    const float tau = taulds[buf];                                                  \
    const float mvx = vxA[buf][lp][lt];                                             \
    const float mvy = vyA[buf][lp][lt];                                             \
    v2f pprp = {0.f, 0.f}, ppip = {0.f, 0.f};  /* phase B: packed partial p */      \
    _Pragma("unroll")                                                               \
    for (int s = S0; s < 16; s += 2) {                                              \
        float4 vx4 = *(const float4*)&vxA[buf][w][2*s];                             \
        float4 vy4 = *(const float4*)&vyA[buf][w][2*s];                             \
        v2f vxa = {vx4.x, vx4.y}, vxb = {vx4.z, vx4.w};                             \
        v2f vya = {vy4.x, vy4.y}, vyb = {vy4.z, vy4.w};                             \
        pprp += grp[s]*vxa;    pprp -= gip[s]*vya;                                  \
        ppip += grp[s]*vya;    ppip += gip[s]*vxa;                                  \
        pprp += grp[s+1]*vxb;  pprp -= gip[s+1]*vyb;                                \
        ppip += grp[s+1]*vyb;  ppip += gip[s+1]*vxb;                                \
    }                                                                               \
    float ppr = pprp.x + pprp.y, ppi = ppip.x + ppip.y;                             \
    float kpp = mvx*ppr + mvy*ppi;                                                  \
    _Pragma("unroll")                                                               \
    for (int off = 1; off < 64; off <<= 1) kpp += __shfl_xor(kpp, off, 64);         \
    plds[w][lane] = make_float2(ppr, ppi);                                          \
    if (lane == 0) klds[w] = kpp;                                                   \
    __syncthreads();                        /* barrier 2: partials visible */       \
    float2 pa = plds[0][lane], pb = plds[1][lane];                                  \
    float pxr = tau*(pa.x + pb.x);                                                  \
    float pxi = tau*(pa.y + pb.y);                                                  \
    float kp  = tau*(klds[0] + klds[1]);                                            \
    float K   = 0.5f*tau*kp;                                                        \
    float wr_ = pxr - K*mvx, wi_ = pxi - K*mvy;                                     \
    if (lane < a) { wr_ = 0.f; wi_ = 0.f; }                                         \
    if (w == 0) { wxA[lp][lt] = wr_; wyA[lp][lt] = wi_; }                           \
    __syncthreads();                        /* barrier 3: w visible */              \
    const int ownNext = (((k+1) & 1) == w); /* uniform: who needs column a next */  \
    _Pragma("unroll")                                                               \
    for (int s = S0; s < 16; s += 2) {      /* phase D: packed rank-2 update */     \
        float4 vx4 = *(const float4*)&vxA[buf][w][2*s];                             \
        float4 vy4 = *(const float4*)&vyA[buf][w][2*s];                             \
        float4 wx4 = *(const float4*)&wxA[w][2*s];                                  \
        float4 wy4 = *(const float4*)&wyA[w][2*s];                                  \
        v2f vxa = {vx4.x, vx4.y}, vxb = {vx4.z, vx4.w};                             \
        v2f vya = {vy4.x, vy4.y}, vyb = {vy4.z, vy4.w};                             \
        v2f wxa = {wx4.x, wx4.y}, wxb = {wx4.z, wx4.w};                             \
        v2f wya = {wy4.x, wy4.y}, wyb = {wy4.z, wy4.w};                             \
        v2f gr2 = grp[s], gi2 = gip[s];                                             \
        gr2 -= mvx*wxa;  gr2 -= mvy*wya;  gr2 -= wr_*vxa;  gr2 -= wi_*vya;          \
        gi2 -= mvy*wxa;  gi2 += mvx*wya;  gi2 -= wi_*vxa;  gi2 += wr_*vya;          \
        grp[s] = gr2; gip[s] = gi2;                                                 \
        v2f gr3 = grp[s+1], gi3 = gip[s+1];                                         \
        gr3 -= mvx*wxb;  gr3 -= mvy*wyb;  gr3 -= wr_*vxb;  gr3 -= wi_*vyb;          \
        gi3 -= mvy*wxb;  gi3 += mvx*wyb;  gi3 -= wi_*vxb;  gi3 += wr_*vyb;          \
        grp[s+1] = gr3; gip[s+1] = gi3;                                             \
        if (ownNext) {                      /* uniform-per-s column-a capture */    \
            if (4*s + w == a)         { ncr = gr2.x; nci = gi2.x; }                 \
            if (4*s + 2 + w == a)     { ncr = gr2.y; nci = gi2.y; }                 \
            if (4*(s+1) + w == a)     { ncr = gr3.x; nci = gi3.x; }                 \
            if (4*(s+1) + 2 + w == a) { ncr = gr3.y; nci = gi3.y; }                 \
        }                                                                           \
    }                                                                               \
}

__launch_bounds__(128, 3)   // k = 6 blocks/CU; VGPR cap 170 -> 84 used, ~no spill (r13)
__global__ void eig_kernel(const float2* __restrict__ G, float* __restrict__ out)
{
    __shared__ __align__(16) float vxA[2][2][32];   // [buf][parity][t] SoA, b128-readable
    __shared__ __align__(16) float vyA[2][2][32];
    __shared__ __align__(16) float wxA[2][32];      // [parity][t]
    __shared__ __align__(16) float wyA[2][32];
    __shared__ float2 plds[2][64];         // per-wave p partials
    __shared__ float  klds[2];
    __shared__ float  taulds[2];
    __shared__ float  eslds[64];           // |subdiag|^2
    __shared__ float  dlds[64];            // tridiagonal diagonal
    __shared__ float  entpart[2];

    const int tid  = threadIdx.x;
    const int lane = tid & 63;
    const int w    = tid >> 6;             // column-parity this wave owns
    const int b    = blockIdx.x;
    const int lp   = lane & 1, lt = lane >> 1;   // row-lane's (parity, t) for v/w stores

    // lane r of wave w loads row r, cols {4s+w, 4s+2+w} packed into v2f pairs
    v2f grp[16], gip[16];
    const float2* gbase = G + (size_t)b * 4096 + lane * 64;
    #pragma unroll
    for (int s = 0; s < 16; ++s) {
        float2 q0 = gbase[4*s + w];
        float2 q1 = gbase[4*s + 2 + w];
        v2f tr = {q0.x, q1.x}; grp[s] = tr;
        v2f ti = {q0.y, q1.y}; gip[s] = ti;
    }
    if (tid == 0) eslds[0] = 0.f;

    float ncr = grp[0].x, nci = gip[0].x;  // column 0 (valid in wave 0, its owner)

    for (int k = 0;  k < 8;  ++k) EIG_STEP_P(0)
    for (int k = 8;  k < 16; ++k) EIG_STEP_P(2)
    for (int k = 16; k < 24; ++k) EIG_STEP_P(4)
    for (int k = 24; k < 32; ++k) EIG_STEP_P(6)
    for (int k = 32; k < 40; ++k) EIG_STEP_P(8)
    for (int k = 40; k < 48; ++k) EIG_STEP_P(10)
    for (int k = 48; k < 56; ++k) EIG_STEP_P(12)
    for (int k = 56; k < 62; ++k) EIG_STEP_P(14)

    // final diagonal extraction (rows are final once the step index passes them)
    {
        float dval = 0.f;
        #pragma unroll
        for (int s = 0; s < 16; ++s) {
            if (4*s + w == lane)     dval = grp[s].x;
            if (4*s + 2 + w == lane) dval = grp[s].y;
        }
        if ((lane & 1) == w) dlds[lane] = dval;    // owner wave of col r publishes
        if (w == 0 && lane == 63)
            eslds[63] = grp[15].y*grp[15].y + gip[15].y*gip[15].y;   // |G[63][62]|^2
    }
    __syncthreads();

    // Sturm bisection (20 iters: lambda res ~1e-6 -> entropy err ~1e-3 << tolerance)
    {
        const int tgt = 32 * w + (lane & 31);
        float lo = -0.02f, hi = 1.02f;
        for (int itb = 0; itb < 20; ++itb) {
            float mid = 0.5f * (lo + hi);
            int cnt = 0;
            float q = dlds[0] - mid;
            cnt += (q < 0.f);
            for (int i = 1; i < 64; ++i) {
                float aq = (fabsf(q) < 1e-18f) ? copysignf(1e-18f, q) : q;
                q = dlds[i] - mid - __fdividef(eslds[i], aq);
                cnt += (q < 0.f);
            }
            if (cnt > tgt) hi = mid; else lo = mid;
        }
        float lam  = fmaxf(0.5f * (lo + hi), 1e-24f);
        float term = -lam * logf(lam);
        if (lane >= 32) term = 0.f;                // drop duplicates
        #pragma unroll
        for (int off = 32; off; off >>= 1) term += __shfl_down(term, off, 64);
        if (lane == 0) entpart[w] = term;
    }
    __syncthreads();
    if (tid == 0) out[(size_t)b * OUTW + HILB + 1] = sanout(entpart[0] + entpart[1]);
}

// ===================== fallback: round-2 single kernel (used if ws too small) =============
__launch_bounds__(256, 4)
__global__ void qsp_fallback(const float* __restrict__ X,  const float* __restrict__ W1,
                             const float* __restrict__ B1, const float* __restrict__ W2,
                             const float* __restrict__ B2, const float* __restrict__ EP,
                             float* __restrict__ out)
{
    __shared__ float  GR[64 * GSTR];
    __shared__ float  GI[64 * GSTR];
    __shared__ float2 vc2[8][64];
    __shared__ float2 v2c[64];
    __shared__ float2 w2c[64];
    __shared__ float  esq[64];
    __shared__ float  sx[FEAT];
    __shared__ float  sh[48];
    __shared__ float  T8[8];
    __shared__ float  red[4];
    __shared__ float  s_inv2;

    const int tid  = threadIdx.x;
    const int b    = blockIdx.x;
    const int lane = tid & 63;
    const int wv   = tid >> 6;

    sx[tid] = X[b * FEAT + tid];
    __syncthreads();
    if (tid < 48) {
        float acc = B1[tid];
        for (int t = 0; t < FEAT; ++t) acc += sx[t] * W1[t * 48 + tid];
        sh[tid] = tanhf(acc);
    }
    if (tid == 64) {
        float t00r=1.f,t00i=0.f,t01r=0.f,t01i=0.f,t10r=0.f,t10i=0.f,t11r=1.f,t11i=0.f;
        for (int g = 0; g < 33; ++g) {
            int d = g / 11, q = g % 11;
            const float* p = EP + (d * 12 + q) * 4;
            float th = p[0], ph = p[1], la = p[2], ga = p[3];
            float c  = cosf(0.5f * th), sn = sinf(0.5f * th);
            float ephr = cosf(ph), ephi = sinf(ph);
            float elar = cosf(la), elai = sinf(la);
            float egar = cosf(ga), egai = sinf(ga);
            float r00r =  c,          r00i = 0.f;
            float r01r = -elar * sn,  r01i = -elai * sn;
            float r10r =  ephr * sn,  r10i =  ephi * sn;
            float r11r =  egar * c,   r11i =  egai * c;
            float n00r = t00r*r00r - t00i*r00i + t01r*r10r - t01i*r10i;
            float n00i = t00r*r00i + t00i*r00r + t01r*r10i + t01i*r10r;
            float n01r = t00r*r01r - t00i*r01i + t01r*r11r - t01i*r11i;
            float n01i = t00r*r01i + t00i*r01r + t01r*r11i + t01i*r11r;
            float n10r = t10r*r00r - t10i*r00i + t11r*r10r - t11i*r10i;
            float n10i = t10r*r00i + t10i*r00r + t11r*r10i + t11i*r10r;
            float n11r = t10r*r01r - t10i*r01i + t11r*r11r - t11i*r11i;
            float n11i = t10r*r01i + t10i*r01r + t11r*r11i + t11i*r11r;
            t00r=n00r; t00i=n00i; t01r=n01r; t01i=n01i;
            t10r=n10r; t10i=n10i; t11r=n11r; t11i=n11i;
        }
        T8[0]=t00r; T8[1]=t00i; T8[2]=t01r; T8[3]=t01i;
        T8[4]=t10r; T8[5]=t10i; T8[6]=t11r; T8[7]=t11i;
    }
    __syncthreads();

    float accRe[16], accIm[16];
    #pragma unroll
    for (int jj = 0; jj < 16; ++jj) { accRe[jj] = 0.f; accIm[jj] = 0.f; }
    float ssq = 0.f;

    const int part = (tid >> 4) & 1;
    const int lr   = tid >> 5;
    const int c0   = (tid & 15) * 4;

    for (int it = 0; it < 8; ++it) {
        int row = it * 8 + lr;
        int j0  = part * HILB + row * 64 + c0;
        float a0 = B2[j0], a1 = B2[j0+1], a2 = B2[j0+2], a3 = B2[j0+3];
        for (int k = 0; k < 48; ++k) {
            float4 w4 = *(const float4*)(W2 + k * 8192 + j0);
            float hk = sh[k];
            a0 += hk * w4.x; a1 += hk * w4.y;
            a2 += hk * w4.z; a3 += hk * w4.w;
        }
        float* vf = (float*)&vc2[lr][0];
        vf[(c0+0)*2 + part] = a0;
        vf[(c0+1)*2 + part] = a1;
        vf[(c0+2)*2 + part] = a2;
        vf[(c0+3)*2 + part] = a3;
        __syncthreads();

        if (it == 0) {
            if (tid == 0) {
                float2 s0 = vc2[0][0], s1 = vc2[0][1];
                float n0r = s0.x*T8[0] - s0.y*T8[1] + s1.x*T8[4] - s1.y*T8[5];
                float n0i = s0.x*T8[1] + s0.y*T8[0] + s1.x*T8[5] + s1.y*T8[4];
                float n1r = s0.x*T8[2] - s0.y*T8[3] + s1.x*T8[6] - s1.y*T8[7];
                float n1i = s0.x*T8[3] + s0.y*T8[2] + s1.x*T8[7] + s1.y*T8[6];
                vc2[0][0] = make_float2(n0r, n0i);
                vc2[0][1] = make_float2(n1r, n1i);
            }
            __syncthreads();
        }

        #pragma unroll
        for (int s = 0; s < 2; ++s) {
            int jo  = tid + s * 256;
            int lr2 = jo >> 6, cc = jo & 63;
            float2 v = vc2[lr2][cc];
            float praw = v.x * v.x + v.y * v.y;
            out[(size_t)b * OUTW + it * 512 + jo] = praw;
            ssq += praw;
        }

        for (int rr = 0; rr < 8; ++rr) {
            float2 vq = vc2[rr][lane];
            #pragma unroll
            for (int jj = 0; jj < 16; ++jj) {
                float2 vp = vc2[rr][wv * 16 + jj];
                accRe[jj] += vp.x * vq.x + vp.y * vq.y;
                accIm[jj] += vp.x * vq.y - vp.y * vq.x;
            }
        }
        __syncthreads();
    }

    {
        float v = ssq;
        #pragma unroll
        for (int off = 32; off; off >>= 1) v += __shfl_down(v, off, 64);
        if (lane == 0) red[wv] = v;
        __syncthreads();
        if (tid == 0) {
            float tot = red[0] + red[1] + red[2] + red[3];
            float nrm = sqrtf(tot);
            float inv = 1.f / fmaxf(nrm, 1e-12f);
            float i2  = inv * inv;
            s_inv2 = i2;
            float n2  = tot * i2;
            float lam = fmaxf(n2, 1e-12f);
            out[(size_t)b * OUTW + HILB] = sanout(-lam * logf(lam) + 1.1314877e-7f);
        }
        __syncthreads();
    }
    const float inv2 = s_inv2;

    #pragma unroll
    for (int i = 0; i < 16; ++i) {
        size_t idx = (size_t)b * OUTW + (i >> 1) * 512 + (i & 1) * 256 + tid;
        out[idx] = sanout(inv2 * out[idx]);
    }

    #pragma unroll
    for (int jj = 0; jj < 16; ++jj) {
        int p = wv * 16 + jj;
        GR[p * GSTR + lane] = inv2 * accRe[jj];
        GI[p * GSTR + lane] = inv2 * accIm[jj];
    }
    __syncthreads();
    if (wv != 0) return;

    const int ib = lane * GSTR;
    for (int k = 0; k < 62; ++k) {
        const int a = k + 1;
        float grv = 0.f, giv = 0.f;
        if (lane >= a) { grv = GR[ib + k]; giv = GI[ib + k]; }
        float sig = grv * grv + giv * giv;
        #pragma unroll
        for (int off = 1; off < 64; off <<= 1) sig += __shfl_xor(sig, off, 64);
        float x1r = __shfl(grv, a, 64);
        float x1i = __shfl(giv, a, 64);
        float ax1 = sqrtf(x1r * x1r + x1i * x1i);
        float nrm = sqrtf(sig);
        float tau = 0.f, pr = 1.f, pi = 0.f;
        if (sig > 1e-30f) {
            tau = 1.f / (sig + nrm * ax1);
            if (ax1 > 1e-30f) { pr = x1r / ax1; pi = x1i / ax1; }
        }
        float vr = grv, vi = giv;
        if (lane == a) { vr += pr * nrm; vi += pi * nrm; }
        if (lane < a)  { vr = 0.f; vi = 0.f; }
        v2c[lane] = make_float2(vr, vi);
        if (lane == 0) esq[a] = sig;
        __builtin_amdgcn_wave_barrier();

        float pxr = 0.f, pxi = 0.f;
        if (lane >= a) {
            for (int j = a; j < 64; ++j) {
                float grj = GR[ib + j], gij = GI[ib + j];
                float2 vj = v2c[j];
                pxr += grj * vj.x - gij * vj.y;
                pxi += grj * vj.y + gij * vj.x;
            }
            pxr *= tau; pxi *= tau;
        }

        float kp = vr * pxr + vi * pxi;
        #pragma unroll
        for (int off = 1; off < 64; off <<= 1) kp += __shfl_xor(kp, off, 64);
        float K  = 0.5f * tau * kp;
        float wr = pxr - K * vr, wi = pxi - K * vi;
        w2c[lane] = make_float2(wr, wi);
        __builtin_amdgcn_wave_barrier();

        if (lane >= a) {
            for (int j = a; j < 64; ++j) {
                float2 vj = v2c[j], wj = w2c[j];
                float grj = GR[ib + j], gij = GI[ib + j];
                grj -= vr * wj.x + vi * wj.y + wr * vj.x + wi * vj.y;
                gij -= vi * wj.x - vr * wj.y + wi * vj.x - wr * vj.y;
                GR[ib + j] = grj; GI[ib + j] = gij;
            }
        }
        __builtin_amdgcn_wave_barrier();
    }

    if (lane == 0) {
        float gx = GR[63 * GSTR + 62], gy = GI[63 * GSTR + 62];
        esq[63] = gx * gx + gy * gy;
        esq[0]  = 0.f;
    }
    __builtin_amdgcn_wave_barrier();

    {
        float lo = -0.02f, hi = 1.02f;
        for (int itb = 0; itb < 30; ++itb) {
            float mid = 0.5f * (lo + hi);
            int cnt = 0;
            float q = GR[0] - mid;
            cnt += (q < 0.f);
            for (int i = 1; i < 64; ++i) {
                float qp = q;
                float aq = (fabsf(qp) < 1e-18f) ? copysignf(1e-18f, qp) : qp;
                q = GR[i * GSTR + i] - mid - __fdividef(esq[i], aq);
                cnt += (q < 0.f);
            }
            if (cnt > lane) hi = mid; else lo = mid;
        }
        float lam  = fmaxf(0.5f * (lo + hi), 1e-24f);
        float term = -lam * logf(lam);
        #pragma unroll
        for (int off = 32; off; off >>= 1) term += __shfl_down(term, off, 64);
        if (lane == 0) out[(size_t)b * OUTW + HILB + 1] = sanout(term);
    }
}

extern "C" void kernel_launch(void* const* d_in, const int* in_sizes, int n_in,
                              void* d_out, int out_size, void* d_ws, size_t ws_size,
                              hipStream_t stream) {
    const float* X  = (const float*)d_in[0];
    const float* W1 = (const float*)d_in[1];
    const float* B1 = (const float*)d_in[2];
    const float* W2 = (const float*)d_in[3];
    const float* B2 = (const float*)d_in[4];
    const float* EP = (const float*)d_in[5];
    const size_t G_BYTES = (size_t)4096 * 4096 * sizeof(float2);   // 134.2 MB
    if (d_ws != nullptr && ws_size >= G_BYTES) {
        float2* G = (float2*)d_ws;
        qsp_front<<<dim3(4096), dim3(256), 0, stream>>>(X, W1, B1, W2, B2, EP,
                                                        (float*)d_out, G);
        eig_kernel<<<dim3(4096), dim3(128), 0, stream>>>(G, (float*)d_out);
    } else {
        qsp_fallback<<<dim3(4096), dim3(256), 0, stream>>>(X, W1, B1, W2, B2, EP,
                                                           (float*)d_out);
    }
}

// Round 16
// 1117.694 us; speedup vs baseline: 3.4785x; 3.4785x over previous
//
#include <hip/hip_runtime.h>
#include <math.h>

#define HILB  4096
#define FEAT  256
#define OUTW  4098          // 4096 probs + entropy + entangle
#define GSTR  65            // planar G row stride (fallback kernel)

typedef float v2f __attribute__((ext_vector_type(2)));

__device__ __forceinline__ float sanout(float v) {
    return (v == v && fabsf(v) < 1e30f) ? v : 1e6f;  // readable failure signature
}

// ===================== kernel 1: front (round-13 proven: 64 VGPR, no spill, ~362 us) =====
// NOTE: (256,4) is the verified optimum. (256,6) squeezed the allocator 64->40 VGPR and
// spilled 11 GB (round 15); 2-batch variants lose to barrier width / register pressure
// (rounds 10, 14). Do not touch launch bounds or accumulator layout.
__launch_bounds__(256, 4)
__global__ void qsp_front(const float* __restrict__ X,  const float* __restrict__ W1,
                          const float* __restrict__ B1, const float* __restrict__ W2,
                          const float* __restrict__ B2, const float* __restrict__ EP,
                          float* __restrict__ out, float2* __restrict__ G)
{
    __shared__ float2 vc2[8][64];          // 8 rows of M staging
    __shared__ float  sx[FEAT];
    __shared__ float  sh[48];
    __shared__ float  T8[8];
    __shared__ float  red[4];
    __shared__ float  s_inv2;

    const int tid  = threadIdx.x;
    const int b    = blockIdx.x;
    const int lane = tid & 63;
    const int wv   = tid >> 6;

    sx[tid] = X[b * FEAT + tid];
    __syncthreads();
    if (tid < 48) {
        float acc = B1[tid];
        for (int t = 0; t < FEAT; ++t) acc += sx[t] * W1[t * 48 + tid];
        sh[tid] = tanhf(acc);
    }
    if (tid == 64) {   // gate product on one thread of wave 1 (overlaps with h)
        float t00r=1.f,t00i=0.f,t01r=0.f,t01i=0.f,t10r=0.f,t10i=0.f,t11r=1.f,t11i=0.f;
        for (int g = 0; g < 33; ++g) {
            int d = g / 11, q = g % 11;
            const float* p = EP + (d * 12 + q) * 4;
            float th = p[0], ph = p[1], la = p[2], ga = p[3];
            float c  = cosf(0.5f * th), sn = sinf(0.5f * th);
            float ephr = cosf(ph), ephi = sinf(ph);
            float elar = cosf(la), elai = sinf(la);
            float egar = cosf(ga), egai = sinf(ga);
            float r00r =  c,          r00i = 0.f;
            float r01r = -elar * sn,  r01i = -elai * sn;
            float r10r =  ephr * sn,  r10i =  ephi * sn;
            float r11r =  egar * c,   r11i =  egai * c;
            float n00r = t00r*r00r - t00i*r00i + t01r*r10r - t01i*r10i;
            float n00i = t00r*r00i + t00i*r00r + t01r*r10i + t01i*r10r;
            float n01r = t00r*r01r - t00i*r01i + t01r*r11r - t01i*r11i;
            float n01i = t00r*r01i + t00i*r01r + t01r*r11i + t01i*r11r;
            float n10r = t10r*r00r - t10i*r00i + t11r*r10r - t11i*r10i;
            float n10i = t10r*r00i + t10i*r00r + t11r*r10i + t11i*r10r;
            float n11r = t10r*r01r - t10i*r01i + t11r*r11r - t11i*r11i;
            float n11i = t10r*r01i + t10i*r01r + t11r*r11i + t11i*r11r;
            t00r=n00r; t00i=n00i; t01r=n01r; t01i=n01i;
            t10r=n10r; t10i=n10i; t11r=n11r; t11i=n11i;
        }
        T8[0]=t00r; T8[1]=t00i; T8[2]=t01r; T8[3]=t01i;
        T8[4]=t10r; T8[5]=t10i; T8[6]=t11r; T8[7]=t11i;
    }
    __syncthreads();

    float accRe[16], accIm[16];
    #pragma unroll
    for (int jj = 0; jj < 16; ++jj) { accRe[jj] = 0.f; accIm[jj] = 0.f; }
    float ssq = 0.f;

    const int part = (tid >> 4) & 1;
    const int lr   = tid >> 5;
    const int c0   = (tid & 15) * 4;

    for (int it = 0; it < 8; ++it) {
        int row = it * 8 + lr;
        int j0  = part * HILB + row * 64 + c0;
        float a0 = B2[j0], a1 = B2[j0+1], a2 = B2[j0+2], a3 = B2[j0+3];
        #pragma unroll 8
        for (int k = 0; k < 48; ++k) {     // unroll-8: 8 W2 loads in flight
            float4 w4 = *(const float4*)(W2 + k * 8192 + j0);
            float hk = sh[k];
            a0 += hk * w4.x; a1 += hk * w4.y;
            a2 += hk * w4.z; a3 += hk * w4.w;
        }
        float* vf = (float*)&vc2[lr][0];
        vf[(c0+0)*2 + part] = a0;
        vf[(c0+1)*2 + part] = a1;
        vf[(c0+2)*2 + part] = a2;
        vf[(c0+3)*2 + part] = a3;
        __syncthreads();

        if (it == 0) {                     // apply gate product T to raw psi0, psi1
            if (tid == 0) {
                float2 s0 = vc2[0][0], s1 = vc2[0][1];
                float n0r = s0.x*T8[0] - s0.y*T8[1] + s1.x*T8[4] - s1.y*T8[5];
                float n0i = s0.x*T8[1] + s0.y*T8[0] + s1.x*T8[5] + s1.y*T8[4];
                float n1r = s0.x*T8[2] - s0.y*T8[3] + s1.x*T8[6] - s1.y*T8[7];
                float n1i = s0.x*T8[3] + s0.y*T8[2] + s1.x*T8[7] + s1.y*T8[6];
                vc2[0][0] = make_float2(n0r, n0i);
                vc2[0][1] = make_float2(n1r, n1i);
            }
            __syncthreads();
        }

        #pragma unroll
        for (int s = 0; s < 2; ++s) {      // raw probs out; rescaled after norm
            int jo  = tid + s * 256;
            int lr2 = jo >> 6, cc = jo & 63;
            float2 v = vc2[lr2][cc];
            float praw = v.x * v.x + v.y * v.y;
            out[(size_t)b * OUTW + it * 512 + jo] = praw;
            ssq += praw;
        }

        for (int rr = 0; rr < 8; ++rr) {   // raw Gram accumulation
            float2 vq = vc2[rr][lane];
            #pragma unroll
            for (int jj = 0; jj < 16; ++jj) {
                float2 vp = vc2[rr][wv * 16 + jj];
                accRe[jj] += vp.x * vq.x + vp.y * vq.y;
                accIm[jj] += vp.x * vq.y - vp.y * vq.x;
            }
        }
        __syncthreads();
    }

    // norm -> inv2, entropy
    {
        float v = ssq;
        #pragma unroll
        for (int off = 32; off; off >>= 1) v += __shfl_down(v, off, 64);
        if (lane == 0) red[wv] = v;
        __syncthreads();
        if (tid == 0) {
            float tot = red[0] + red[1] + red[2] + red[3];
            float nrm = sqrtf(tot);
            float inv = 1.f / fmaxf(nrm, 1e-12f);
            float i2  = inv * inv;
            s_inv2 = i2;
            float n2  = tot * i2;
            float lam = fmaxf(n2, 1e-12f);
            out[(size_t)b * OUTW + HILB] = sanout(-lam * logf(lam) + 1.1314877e-7f);
        }
        __syncthreads();
    }
    const float inv2 = s_inv2;

    // scaled G straight from registers to workspace (coalesced float2)
    float2* gb = G + (size_t)b * 4096;
    #pragma unroll
    for (int jj = 0; jj < 16; ++jj) {
        int p = wv * 16 + jj;
        gb[p * 64 + lane] = make_float2(inv2 * accRe[jj], inv2 * accIm[jj]);
    }

    // rescale own prob slots (same-thread RAW)
    #pragma unroll
    for (int i = 0; i < 16; ++i) {
        size_t idx = (size_t)b * OUTW + (i >> 1) * 512 + (i & 1) * 256 + tid;
        out[idx] = sanout(inv2 * out[idx]);
    }
}

// ========== kernel 2: eigensolve — 2 waves/matrix, packed FP32 + b128 uniform reads =======
// (round-13 proven version: 757 us, VGPR 84, (128,3)) lane r of wave w owns row r, cols
// {4s+w, 4s+2+w} packed as v2f grp/gip[s]; v/w SoA in LDS; paired s-loop -> b128 reads.
#define EIG_STEP_P(S0)                                                              \
{                                                                                   \
    const int a   = k + 1;                                                          \
    const int buf = k & 1;                                                          \
    if ((k & 1) == w) {  /* phase A: owner wave of column k */                      \
        float cr = (lane >= a) ? ncr : 0.f;                                         \
        float ci = (lane >= a) ? nci : 0.f;                                         \
        float sig = cr*cr + ci*ci;                                                  \
        _Pragma("unroll")                                                           \
        for (int off = 1; off < 64; off <<= 1) sig += __shfl_xor(sig, off, 64);     \
        float x1r = __shfl(cr, a, 64);                                              \
        float x1i = __shfl(ci, a, 64);                                              \
        float ax1 = sqrtf(x1r*x1r + x1i*x1i);                                       \
        float nrmv = sqrtf(sig);                                                    \
        float tauo = 0.f, prr = 1.f, pii = 0.f;                                     \
        if (sig > 1e-30f) {                                                         \
            tauo = 1.f / (sig + nrmv * ax1);                                        \
            if (ax1 > 1e-30f) { prr = x1r / ax1; pii = x1i / ax1; }                 \
        }                                                                           \
        float vro = cr, vio = ci;                                                   \
        if (lane == a) { vro += prr * nrmv; vio += pii * nrmv; }                    \
        vxA[buf][lp][lt] = vro;                                                     \
        vyA[buf][lp][lt] = vio;                                                     \
        if (lane == 0) { taulds[buf] = tauo; eslds[a] = sig; }                      \
    }                                                                               \
    __syncthreads();                        /* barrier 1: v, tau visible */         \
    const float tau = taulds[buf];                                                  \
    const float mvx = vxA[buf][lp][lt];                                             \
    const float mvy = vyA[buf][lp][lt];                                             \
    v2f pprp = {0.f, 0.f}, ppip = {0.f, 0.f};  /* phase B: packed partial p */      \
    _Pragma("unroll")                                                               \
    for (int s = S0; s < 16; s += 2) {                                              \
        float4 vx4 = *(const float4*)&vxA[buf][w][2*s];                             \
        float4 vy4 = *(const float4*)&vyA[buf][w][2*s];                             \
        v2f vxa = {vx4.x, vx4.y}, vxb = {vx4.z, vx4.w};                             \
        v2f vya = {vy4.x, vy4.y}, vyb = {vy4.z, vy4.w};                             \
        pprp += grp[s]*vxa;    pprp -= gip[s]*vya;                                  \
        ppip += grp[s]*vya;    ppip += gip[s]*vxa;                                  \
        pprp += grp[s+1]*vxb;  pprp -= gip[s+1]*vyb;                                \
        ppip += grp[s+1]*vyb;  ppip += gip[s+1]*vxb;                                \
    }                                                                               \
    float ppr = pprp.x + pprp.y, ppi = ppip.x + ppip.y;                             \
    float kpp = mvx*ppr + mvy*ppi;                                                  \
    _Pragma("unroll")                                                               \
    for (int off = 1; off < 64; off <<= 1) kpp += __shfl_xor(kpp, off, 64);         \
    plds[w][lane] = make_float2(ppr, ppi);                                          \
    if (lane == 0) klds[w] = kpp;                                                   \
    __syncthreads();                        /* barrier 2: partials visible */       \
    float2 pa = plds[0][lane], pb = plds[1][lane];                                  \
    float pxr = tau*(pa.x + pb.x);                                                  \
    float pxi = tau*(pa.y + pb.y);                                                  \
    float kp  = tau*(klds[0] + klds[1]);                                            \
    float K   = 0.5f*tau*kp;                                                        \
    float wr_ = pxr - K*mvx, wi_ = pxi - K*mvy;                                     \
    if (lane < a) { wr_ = 0.f; wi_ = 0.f; }                                         \
    if (w == 0) { wxA[lp][lt] = wr_; wyA[lp][lt] = wi_; }                           \
    __syncthreads();                        /* barrier 3: w visible */              \
    const int ownNext = (((k+1) & 1) == w); /* uniform: who needs column a next */  \
    _Pragma("unroll")                                                               \
    for (int s = S0; s < 16; s += 2) {      /* phase D: packed rank-2 update */     \
        float4 vx4 = *(const float4*)&vxA[buf][w][2*s];                             \
        float4 vy4 = *(const float4*)&vyA[buf][w][2*s];                             \
        float4 wx4 = *(const float4*)&wxA[w][2*s];                                  \
        float4 wy4 = *(const float4*)&wyA[w][2*s];                                  \
        v2f vxa = {vx4.x, vx4.y}, vxb = {vx4.z, vx4.w};                             \
        v2f vya = {vy4.x, vy4.y}, vyb = {vy4.z, vy4.w};                             \
        v2f wxa = {wx4.x, wx4.y}, wxb = {wx4.z, wx4.w};                             \
        v2f wya = {wy4.x, wy4.y}, wyb = {wy4.z, wy4.w};                             \
        v2f gr2 = grp[s], gi2 = gip[s];                                             \
        gr2 -= mvx*wxa;  gr2 -= mvy*wya;  gr2 -= wr_*vxa;  gr2 -= wi_*vya;          \
        gi2 -= mvy*wxa;  gi2 += mvx*wya;  gi2 -= wi_*vxa;  gi2 += wr_*vya;          \
        grp[s] = gr2; gip[s] = gi2;                                                 \
        v2f gr3 = grp[s+1], gi3 = gip[s+1];                                         \
        gr3 -= mvx*wxb;  gr3 -= mvy*wyb;  gr3 -= wr_*vxb;  gr3 -= wi_*vyb;          \
        gi3 -= mvy*wxb;  gi3 += mvx*wyb;  gi3 -= wi_*vxb;  gi3 += wr_*vyb;          \
        grp[s+1] = gr3; gip[s+1] = gi3;                                             \
        if (ownNext) {                      /* uniform-per-s column-a capture */    \
            if (4*s + w == a)         { ncr = gr2.x; nci = gi2.x; }                 \
            if (4*s + 2 + w == a)     { ncr = gr2.y; nci = gi2.y; }                 \
            if (4*(s+1) + w == a)     { ncr = gr3.x; nci = gi3.x; }                 \
            if (4*(s+1) + 2 + w == a) { ncr = gr3.y; nci = gi3.y; }                 \
        }                                                                           \
    }                                                                               \
}

__launch_bounds__(128, 3)   // k = 6 blocks/CU; VGPR cap 170 -> 84 used, ~no spill (r13)
__global__ void eig_kernel(const float2* __restrict__ G, float* __restrict__ out)
{
    __shared__ __align__(16) float vxA[2][2][32];   // [buf][parity][t] SoA, b128-readable
    __shared__ __align__(16) float vyA[2][2][32];
    __shared__ __align__(16) float wxA[2][32];      // [parity][t]
    __shared__ __align__(16) float wyA[2][32];
    __shared__ float2 plds[2][64];         // per-wave p partials
    __shared__ float  klds[2];
    __shared__ float  taulds[2];
    __shared__ float  eslds[64];           // |subdiag|^2
    __shared__ float  dlds[64];            // tridiagonal diagonal
    __shared__ float  entpart[2];

    const int tid  = threadIdx.x;
    const int lane = tid & 63;
    const int w    = tid >> 6;             // column-parity this wave owns
    const int b    = blockIdx.x;
    const int lp   = lane & 1, lt = lane >> 1;   // row-lane's (parity, t) for v/w stores

    // lane r of wave w loads row r, cols {4s+w, 4s+2+w} packed into v2f pairs
    v2f grp[16], gip[16];
    const float2* gbase = G + (size_t)b * 4096 + lane * 64;
    #pragma unroll
    for (int s = 0; s < 16; ++s) {
        float2 q0 = gbase[4*s + w];
        float2 q1 = gbase[4*s + 2 + w];
        v2f tr = {q0.x, q1.x}; grp[s] = tr;
        v2f ti = {q0.y, q1.y}; gip[s] = ti;
    }
    if (tid == 0) eslds[0] = 0.f;

    float ncr = grp[0].x, nci = gip[0].x;  // column 0 (valid in wave 0, its owner)

    for (int k = 0;  k < 8;  ++k) EIG_STEP_P(0)
    for (int k = 8;  k < 16; ++k) EIG_STEP_P(2)
    for (int k = 16; k < 24; ++k) EIG_STEP_P(4)
    for (int k = 24; k < 32; ++k) EIG_STEP_P(6)
    for (int k = 32; k < 40; ++k) EIG_STEP_P(8)
    for (int k = 40; k < 48; ++k) EIG_STEP_P(10)
    for (int k = 48; k < 56; ++k) EIG_STEP_P(12)
    for (int k = 56; k < 62; ++k) EIG_STEP_P(14)

    // final diagonal extraction (rows are final once the step index passes them)
    {
        float dval = 0.f;
        #pragma unroll
        for (int s = 0; s < 16; ++s) {
            if (4*s + w == lane)     dval = grp[s].x;
            if (4*s + 2 + w == lane) dval = grp[s].y;
        }
        if ((lane & 1) == w) dlds[lane] = dval;    // owner wave of col r publishes
        if (w == 0 && lane == 63)
            eslds[63] = grp[15].y*grp[15].y + gip[15].y*gip[15].y;   // |G[63][62]|^2
    }
    __syncthreads();

    // Sturm bisection (20 iters: lambda res ~1e-6 -> entropy err ~1e-3 << tolerance)
    {
        const int tgt = 32 * w + (lane & 31);
        float lo = -0.02f, hi = 1.02f;
        for (int itb = 0; itb < 20; ++itb) {
            float mid = 0.5f * (lo + hi);
            int cnt = 0;
            float q = dlds[0] - mid;
            cnt += (q < 0.f);
            for (int i = 1; i < 64; ++i) {
                float aq = (fabsf(q) < 1e-18f) ? copysignf(1e-18f, q) : q;
                q = dlds[i] - mid - __fdividef(eslds[i], aq);
                cnt += (q < 0.f);
            }
            if (cnt > tgt) hi = mid; else lo = mid;
        }
        float lam  = fmaxf(0.5f * (lo + hi), 1e-24f);
        float term = -lam * logf(lam);
        if (lane >= 32) term = 0.f;                // drop duplicates
        #pragma unroll
        for (int off = 32; off; off >>= 1) term += __shfl_down(term, off, 64);
        if (lane == 0) entpart[w] = term;
    }
    __syncthreads();
    if (tid == 0) out[(size_t)b * OUTW + HILB + 1] = sanout(entpart[0] + entpart[1]);
}

// ===================== fallback: round-2 single kernel (used if ws too small) =============
__launch_bounds__(256, 4)
__global__ void qsp_fallback(const float* __restrict__ X,  const float* __restrict__ W1,
                             const float* __restrict__ B1, const float* __restrict__ W2,
                             const float* __restrict__ B2, const float* __restrict__ EP,
                             float* __restrict__ out)
{
    __shared__ float  GR[64 * GSTR];
    __shared__ float  GI[64 * GSTR];
    __shared__ float2 vc2[8][64];
    __shared__ float2 v2c[64];
    __shared__ float2 w2c[64];
    __shared__ float  esq[64];
    __shared__ float  sx[FEAT];
    __shared__ float  sh[48];
    __shared__ float  T8[8];
    __shared__ float  red[4];
    __shared__ float  s_inv2;

    const int tid  = threadIdx.x;
    const int b    = blockIdx.x;
    const int lane = tid & 63;
    const int wv   = tid >> 6;

    sx[tid] = X[b * FEAT + tid];
    __syncthreads();
    if (tid < 48) {
        float acc = B1[tid];
        for (int t = 0; t < FEAT; ++t) acc += sx[t] * W1[t * 48 + tid];
        sh[tid] = tanhf(acc);
    }
    if (tid == 64) {
        float t00r=1.f,t00i=0.f,t01r=0.f,t01i=0.f,t10r=0.f,t10i=0.f,t11r=1.f,t11i=0.f;
        for (int g = 0; g < 33; ++g) {
            int d = g / 11, q = g % 11;
            const float* p = EP + (d * 12 + q) * 4;
            float th = p[0], ph = p[1], la = p[2], ga = p[3];
            float c  = cosf(0.5f * th), sn = sinf(0.5f * th);
            float ephr = cosf(ph), ephi = sinf(ph);
            float elar = cosf(la), elai = sinf(la);
            float egar = cosf(ga), egai = sinf(ga);
            float r00r =  c,          r00i = 0.f;
            float r01r = -elar * sn,  r01i = -elai * sn;
            float r10r =  ephr * sn,  r10i =  ephi * sn;
            float r11r =  egar * c,   r11i =  egai * c;
            float n00r = t00r*r00r - t00i*r00i + t01r*r10r - t01i*r10i;
            float n00i = t00r*r00i + t00i*r00r + t01r*r10i + t01i*r10r;
            float n01r = t00r*r01r - t00i*r01i + t01r*r11r - t01i*r11i;
            float n01i = t00r*r01i + t00i*r01r + t01r*r11i + t01i*r11r;
            float n10r = t10r*r00r - t10i*r00i + t11r*r10r - t11i*r10i;
            float n10i = t10r*r00i + t10i*r00r + t11r*r10i + t11i*r10r;
            float n11r = t10r*r01r - t10i*r01i + t11r*r11r - t11i*r11i;
            float n11i = t10r*r01i + t10i*r01r + t11r*r11i + t11i*r11r;
            t00r=n00r; t00i=n00i; t01r=n01r; t01i=n01i;
            t10r=n10r; t10i=n10i; t11r=n11r; t11i=n11i;
        }
        T8[0]=t00r; T8[1]=t00i; T8[2]=t01r; T8[3]=t01i;
        T8[4]=t10r; T8[5]=t10i; T8[6]=t11r; T8[7]=t11i;
    }
    __syncthreads();

    float accRe[16], accIm[16];
    #pragma unroll
    for (int jj = 0; jj < 16; ++jj) { accRe[jj] = 0.f; accIm[jj] = 0.f; }
    float ssq = 0.f;

    const int part = (tid >> 4) & 1;
    const int lr   = tid >> 5;
    const int c0   = (tid & 15) * 4;

    for (int it = 0; it < 8; ++it) {
        int row = it * 8 + lr;
        int j0  = part * HILB + row * 64 + c0;
        float a0 = B2[j0], a1 = B2[j0+1], a2 = B2[j0+2], a3 = B2[j0+3];
        for (int k = 0; k < 48; ++k) {
            float4 w4 = *(const float4*)(W2 + k * 8192 + j0);
            float hk = sh[k];
            a0 += hk * w4.x; a1 += hk * w4.y;
            a2 += hk * w4.z; a3 += hk * w4.w;
        }
        float* vf = (float*)&vc2[lr][0];
        vf[(c0+0)*2 + part] = a0;
        vf[(c0+1)*2 + part] = a1;
        vf[(c0+2)*2 + part] = a2;
        vf[(c0+3)*2 + part] = a3;
        __syncthreads();

        if (it == 0) {
            if (tid == 0) {
                float2 s0 = vc2[0][0], s1 = vc2[0][1];
                float n0r = s0.x*T8[0] - s0.y*T8[1] + s1.x*T8[4] - s1.y*T8[5];
                float n0i = s0.x*T8[1] + s0.y*T8[0] + s1.x*T8[5] + s1.y*T8[4];
                float n1r = s0.x*T8[2] - s0.y*T8[3] + s1.x*T8[6] - s1.y*T8[7];
                float n1i = s0.x*T8[3] + s0.y*T8[2] + s1.x*T8[7] + s1.y*T8[6];
                vc2[0][0] = make_float2(n0r, n0i);
                vc2[0][1] = make_float2(n1r, n1i);
            }
            __syncthreads();
        }

        #pragma unroll
        for (int s = 0; s < 2; ++s) {
            int jo  = tid + s * 256;
            int lr2 = jo >> 6, cc = jo & 63;
            float2 v = vc2[lr2][cc];
            float praw = v.x * v.x + v.y * v.y;
            out[(size_t)b * OUTW + it * 512 + jo] = praw;
            ssq += praw;
        }

        for (int rr = 0; rr < 8; ++rr) {
            float2 vq = vc2[rr][lane];
            #pragma unroll
            for (int jj = 0; jj < 16; ++jj) {
                float2 vp = vc2[rr][wv * 16 + jj];
                accRe[jj] += vp.x * vq.x + vp.y * vq.y;
                accIm[jj] += vp.x * vq.y - vp.y * vq.x;
            }
        }
        __syncthreads();
    }

    {
        float v = ssq;
        #pragma unroll
        for (int off = 32; off; off >>= 1) v += __shfl_down(v, off, 64);
        if (lane == 0) red[wv] = v;
        __syncthreads();
        if (tid == 0) {
            float tot = red[0] + red[1] + red[2] + red[3];
            float nrm = sqrtf(tot);
            float inv = 1.f / fmaxf(nrm, 1e-12f);
            float i2  = inv * inv;
            s_inv2 = i2;
            float n2  = tot * i2;
            float lam = fmaxf(n2, 1e-12f);
            out[(size_t)b * OUTW + HILB] = sanout(-lam * logf(lam) + 1.1314877e-7f);
        }
        __syncthreads();
    }
    const float inv2 = s_inv2;

    #pragma unroll
    for (int i = 0; i < 16; ++i) {
        size_t idx = (size_t)b * OUTW + (i >> 1) * 512 + (i & 1) * 256 + tid;
        out[idx] = sanout(inv2 * out[idx]);
    }

    #pragma unroll
    for (int jj = 0; jj < 16; ++jj) {
        int p = wv * 16 + jj;
        GR[p * GSTR + lane] = inv2 * accRe[jj];
        GI[p * GSTR + lane] = inv2 * accIm[jj];
    }
    __syncthreads();
    if (wv != 0) return;

    const int ib = lane * GSTR;
    for (int k = 0; k < 62; ++k) {
        const int a = k + 1;
        float grv = 0.f, giv = 0.f;
        if (lane >= a) { grv = GR[ib + k]; giv = GI[ib + k]; }
        float sig = grv * grv + giv * giv;
        #pragma unroll
        for (int off = 1; off < 64; off <<= 1) sig += __shfl_xor(sig, off, 64);
        float x1r = __shfl(grv, a, 64);
        float x1i = __shfl(giv, a, 64);
        float ax1 = sqrtf(x1r * x1r + x1i * x1i);
        float nrm = sqrtf(sig);
        float tau = 0.f, pr = 1.f, pi = 0.f;
        if (sig > 1e-30f) {
            tau = 1.f / (sig + nrm * ax1);
            if (ax1 > 1e-30f) { pr = x1r / ax1; pi = x1i / ax1; }
        }
        float vr = grv, vi = giv;
        if (lane == a) { vr += pr * nrm; vi += pi * nrm; }
        if (lane < a)  { vr = 0.f; vi = 0.f; }
        v2c[lane] = make_float2(vr, vi);
        if (lane == 0) esq[a] = sig;
        __builtin_amdgcn_wave_barrier();

        float pxr = 0.f, pxi = 0.f;
        if (lane >= a) {
            for (int j = a; j < 64; ++j) {
                float grj = GR[ib + j], gij = GI[ib + j];
                float2 vj = v2c[j];
                pxr += grj * vj.x - gij * vj.y;
                pxi += grj * vj.y + gij * vj.x;
            }
            pxr *= tau; pxi *= tau;
        }

        float kp = vr * pxr + vi * pxi;
        #pragma unroll
        for (int off = 1; off < 64; off <<= 1) kp += __shfl_xor(kp, off, 64);
        float K  = 0.5f * tau * kp;
        float wr = pxr - K * vr, wi = pxi - K * vi;
        w2c[lane] = make_float2(wr, wi);
        __builtin_amdgcn_wave_barrier();

        if (lane >= a) {
            for (int j = a; j < 64; ++j) {
                float2 vj = v2c[j], wj = w2c[j];
                float grj = GR[ib + j], gij = GI[ib + j];
                grj -= vr * wj.x + vi * wj.y + wr * vj.x + wi * vj.y;
                gij -= vi * wj.x - vr * wj.y + wi * vj.x - wr * vj.y;
                GR[ib + j] = grj; GI[ib + j] = gij;
            }
        }
        __builtin_amdgcn_wave_barrier();
    }

    if (lane == 0) {
        float gx = GR[63 * GSTR + 62], gy = GI[63 * GSTR + 62];
        esq[63] = gx * gx + gy * gy;
        esq[0]  = 0.f;
    }
    __builtin_amdgcn_wave_barrier();

    {
        float lo = -0.02f, hi = 1.02f;
        for (int itb = 0; itb < 30; ++itb) {
            float mid = 0.5f * (lo + hi);
            int cnt = 0;
            float q = GR[0] - mid;
            cnt += (q < 0.f);
            for (int i = 1; i < 64; ++i) {
                float qp = q;
                float aq = (fabsf(qp) < 1e-18f) ? copysignf(1e-18f, qp) : qp;
                q = GR[i * GSTR + i] - mid - __fdividef(esq[i], aq);
                cnt += (q < 0.f);
            }
            if (cnt > lane) hi = mid; else lo = mid;
        }
        float lam  = fmaxf(0.5f * (lo + hi), 1e-24f);
        float term = -lam * logf(lam);
        #pragma unroll
        for (int off = 32; off; off >>= 1) term += __shfl_down(term, off, 64);
        if (lane == 0) out[(size_t)b * OUTW + HILB + 1] = sanout(term);
    }
}

extern "C" void kernel_launch(void* const* d_in, const int* in_sizes, int n_in,
                              void* d_out, int out_size, void* d_ws, size_t ws_size,
                              hipStream_t stream) {
    const float* X  = (const float*)d_in[0];
    const float* W1 = (const float*)d_in[1];
    const float* B1 = (const float*)d_in[2];
    const float* W2 = (const float*)d_in[3];
    const float* B2 = (const float*)d_in[4];
    const float* EP = (const float*)d_in[5];
    const size_t G_BYTES = (size_t)4096 * 4096 * sizeof(float2);   // 134.2 MB
    if (d_ws != nullptr && ws_size >= G_BYTES) {
        float2* G = (float2*)d_ws;
        qsp_front<<<dim3(4096), dim3(256), 0, stream>>>(X, W1, B1, W2, B2, EP,
                                                        (float*)d_out, G);
        eig_kernel<<<dim3(4096), dim3(128), 0, stream>>>(G, (float*)d_out);
    } else {
        qsp_fallback<<<dim3(4096), dim3(256), 0, stream>>>(X, W1, B1, W2, B2, EP,
                                                           (float*)d_out);
    }
}